// Round 6
// baseline (1230.094 us; speedup 1.0000x reference)
//
#include <hip/hip_runtime.h>
#include <hip/hip_bf16.h>

typedef __hip_bfloat16 bf16;
typedef __attribute__((ext_vector_type(8))) short s8v;   // 8 bf16 (16B)
typedef __attribute__((ext_vector_type(4))) float f4v;   // 4 f32 (C/D frag)

// Branch-free erf (A&S 7.1.26), |err| < 1.5e-7 — exact at bf16 resolution.
__device__ __forceinline__ float erf_approx(float x) {
    float ax = fabsf(x);
    float t = 1.0f / (1.0f + 0.3275911f * ax);
    float p = t * (0.254829592f + t * (-0.284496736f + t * (1.421413741f
              + t * (-1.453152027f + t * 1.061405429f))));
    float r = 1.0f - p * __expf(-ax * ax);
    return copysignf(r, x);
}
__device__ __forceinline__ float gelu_f(float v) {
    return 0.5f * v * (1.f + erf_approx(v * 0.70710678118654752440f));
}
__device__ __forceinline__ unsigned short f2bf_u(float f) {
    bf16 b = __float2bfloat16(f);
    return *(unsigned short*)&b;
}
__device__ __forceinline__ float bfu2f(unsigned short u) {
    bf16 b = *(bf16*)&u;
    return __bfloat162float(b);
}

// ---------------------------------------------------------------------------
__global__ __launch_bounds__(256) void zero_k(float* __restrict__ p, int n) {
    int i = blockIdx.x * 256 + threadIdx.x;
    if (i < n) p[i] = 0.f;
}

// ---------------------------------------------------------------------------
// Convert + K-PERMUTE conv weights W1..W5 fp32 -> bf16.
// Wp[co][kc*64 + s*32 + ci_l] = W[co][kc*32+ci_l][s]  (kc<8, s<2, ci_l<32)
// so that both MFMA operands are k-contiguous 16B runs.
// ---------------------------------------------------------------------------
__global__ __launch_bounds__(256) void wcvt_k(
    const float* __restrict__ w1, const float* __restrict__ w2,
    const float* __restrict__ w3, const float* __restrict__ w4,
    const float* __restrict__ w5, bf16* __restrict__ dst)
{
    int i = blockIdx.x * 256 + threadIdx.x;
    if (i >= 557056) return;
    const float* src; int li;
    if      (i < 131072) { src = w1; li = i; }
    else if (i < 262144) { src = w2; li = i - 131072; }
    else if (i < 393216) { src = w3; li = i - 262144; }
    else if (i < 524288) { src = w4; li = i - 393216; }
    else                 { src = w5; li = i - 524288; }
    int co = li >> 9, rem = li & 511;
    int kc = rem >> 6, rr = rem & 63;
    int s = rr >> 5, cil = rr & 31;
    dst[i] = __float2bfloat16(src[co * 512 + (kc * 32 + cil) * 2 + s]);
}

// ---------------------------------------------------------------------------
// conv0 channel-collapse coefficients (sum over co of v and v^2 as a
// quadratic form in (x0,x1,x2,1)).
// ---------------------------------------------------------------------------
__global__ __launch_bounds__(256) void m0red_k(
    const float* __restrict__ W0, const float* __restrict__ b0, float* __restrict__ coef)
{
    __shared__ float red[256];
    const int co = threadIdx.x;
    float w0 = W0[3 * co], w1 = W0[3 * co + 1], w2 = W0[3 * co + 2], b = b0[co];
    float vals[14] = {w0, w1, w2, b,
                      w0 * w0, w1 * w1, w2 * w2, b * b,
                      2.f * w0 * w1, 2.f * w0 * w2, 2.f * w1 * w2,
                      2.f * w0 * b, 2.f * w1 * b, 2.f * w2 * b};
    for (int k = 0; k < 14; k++) {
        red[co] = vals[k];
        __syncthreads();
        for (int st = 128; st > 0; st >>= 1) {
            if (co < st) red[co] += red[co + st];
            __syncthreads();
        }
        if (co == 0) coef[k] = red[0];
        __syncthreads();
    }
}

// ---------------------------------------------------------------------------
// GN0 stats per node via the collapsed quadratic form. One block per node.
// ---------------------------------------------------------------------------
__global__ __launch_bounds__(256) void c0stats_k(
    const float* __restrict__ x, const float* __restrict__ coef,
    float* __restrict__ mu0, float* __restrict__ rstd0)
{
    __shared__ float xsl[3008];
    __shared__ float red[512];
    const int n = blockIdx.x, tid = threadIdx.x;
    const float* xr = x + (size_t)n * 3000;
    for (int i = tid; i < 750; i += 256) *(float4*)&xsl[4 + 4 * i] = *(const float4*)(xr + 4 * i);
    if (tid < 4) xsl[tid] = 0.f;
    float c[14];
    #pragma unroll
    for (int k = 0; k < 14; k++) c[k] = coef[k];
    __syncthreads();
    float S = 0.f, Q = 0.f;
    if (tid < 250) {
        float f[16];
        #pragma unroll
        for (int k = 0; k < 4; k++) *(float4*)&f[4 * k] = *(const float4*)&xsl[12 * tid + 4 * k];
        #pragma unroll
        for (int j = 0; j < 4; j++) {
            float x0 = f[3 * j + 3], x1 = f[3 * j + 4], x2 = f[3 * j + 5];
            S += c[0] * x0 + c[1] * x1 + c[2] * x2 + c[3];
            Q += c[4] * x0 * x0 + c[5] * x1 * x1 + c[6] * x2 * x2 + c[7]
               + c[8] * x0 * x1 + c[9] * x0 * x2 + c[10] * x1 * x2
               + c[11] * x0 + c[12] * x1 + c[13] * x2;
        }
    }
    red[tid] = S; red[256 + tid] = Q;
    __syncthreads();
    for (int st = 128; st > 0; st >>= 1) {
        if (tid < st) { red[tid] += red[tid + st]; red[256 + tid] += red[256 + tid + st]; }
        __syncthreads();
    }
    if (tid == 0) {
        float m = red[0] * (1.f / 256000.f);
        float var = red[256] * (1.f / 256000.f) - m * m;
        mu0[n] = m;
        rstd0[n] = rsqrtf(var + 1e-5f);
    }
}

// ---------------------------------------------------------------------------
// h0gT[z][t][ci] = gelu(gn0(conv0(x))) bf16, TRANSPOSED layout, node-chunked.
// Block: (t-chunk of 32, node). Thread: oct=tid&31 -> 8 ci, tq=tid>>5 -> 4 t.
// ---------------------------------------------------------------------------
__global__ __launch_bounds__(256) void h0gT_k(
    const float* __restrict__ x, const float* __restrict__ W0,
    const float* __restrict__ b0, const float* __restrict__ g0,
    const float* __restrict__ be0, const float* __restrict__ mu0,
    const float* __restrict__ rstd0, bf16* __restrict__ h0gT, int n0)
{
    __shared__ float xs[96];
    __shared__ float w0s[768];
    __shared__ float aco[256], cco[256];
    const int z = blockIdx.y;
    const int n = n0 + z;
    const int t0 = blockIdx.x * 32;
    const int tid = threadIdx.x;
    for (int i = tid; i < 768; i += 256) w0s[i] = W0[i];
    {
        float mu = mu0[n], rs = rstd0[n];
        float a = rs * g0[tid];
        aco[tid] = a;
        cco[tid] = (b0[tid] - mu) * a + be0[tid];
    }
    if (tid < 96) {
        int xg = 3 * t0 - 1 + tid;
        xs[tid] = (xg >= 0 && xg < 3000) ? x[(size_t)n * 3000 + xg] : 0.f;
    }
    __syncthreads();
    const int oct = tid & 31, ci0 = oct * 8;
    const int tq = tid >> 5;
    #pragma unroll
    for (int u = 0; u < 4; u++) {
        int tl = tq + 8 * u;
        int t = t0 + tl;
        if (t >= 1000) continue;
        float x0 = xs[3 * tl], x1 = xs[3 * tl + 1], x2 = xs[3 * tl + 2];
        ushort4 lo, hi;
        unsigned short* pu = (unsigned short*)&lo;
        #pragma unroll
        for (int jj = 0; jj < 8; jj++) {
            int ci = ci0 + jj;
            float conv = w0s[3 * ci] * x0 + w0s[3 * ci + 1] * x1 + w0s[3 * ci + 2] * x2;
            float v = gelu_f(conv * aco[ci] + cco[ci]);
            if (jj < 4) pu[jj] = f2bf_u(v);
            else ((unsigned short*)&hi)[jj - 4] = f2bf_u(v);
        }
        bf16* orow = h0gT + ((size_t)z * 1000 + t) * 256 + ci0;
        *(ushort4*)orow = lo;
        *(ushort4*)(orow + 4) = hi;
    }
}

// ---------------------------------------------------------------------------
// In-place GN + GELU on transposed conv output [n][T][C] (c = idx & (C-1)).
// ---------------------------------------------------------------------------
template<int C, int T>
__global__ __launch_bounds__(256) void gn_geluT_k(
    bf16* __restrict__ h, const float* __restrict__ ssum, const float* __restrict__ ssq,
    const float* __restrict__ gam, const float* __restrict__ bet, float invCT)
{
    constexpr unsigned CT = (unsigned)C * (unsigned)T;
    constexpr unsigned total = 576u * CT;
    unsigned I = (blockIdx.x * 256u + threadIdx.x) * 8u;
    if (I >= total) return;
    unsigned n = I / CT;
    unsigned c = I & (unsigned)(C - 1);
    float m = ssum[n] * invCT;
    float rs = rsqrtf(ssq[n] * invCT - m * m + 1e-5f);
    float4 g0 = *(const float4*)&gam[c], g1 = *(const float4*)&gam[c + 4];
    float4 b0 = *(const float4*)&bet[c], b1 = *(const float4*)&bet[c + 4];
    float ga[8] = {g0.x, g0.y, g0.z, g0.w, g1.x, g1.y, g1.z, g1.w};
    float be[8] = {b0.x, b0.y, b0.z, b0.w, b1.x, b1.y, b1.z, b1.w};
    s8v v8 = *(s8v*)&h[I];
    unsigned short* uu = (unsigned short*)&v8;
    #pragma unroll
    for (int j = 0; j < 8; j++) {
        float a = rs * ga[j];
        float v = bfu2f(uu[j]) * a + (be[j] - m * a);
        uu[j] = f2bf_u(gelu_f(v));
    }
    *(s8v*)&h[I] = v8;
}

// ===========================================================================
// Barrier-free MFMA conv GEMM. A = activations gT[n][t][ci] (M = t),
// B = permuted weights Wp (N = co). All fragments load DIRECTLY from global
// (k-contiguous b128); no LDS, no __syncthreads in the K-loop.
// Output hout[n][t][co] (transposed, feeds next layer) + GN stat atomics.
// ===========================================================================
template<int TW, int CW, int MW, int NW>
__global__ __launch_bounds__(256, 4) void convG_k(
    const bf16* __restrict__ g, const bf16* __restrict__ Wp,
    const float* __restrict__ bias, bf16* __restrict__ hout,
    float* __restrict__ ssum, float* __restrict__ ssq,
    int T_g, int T_out, int n0)
{
    constexpr int CO = CW * NW * 16;
    constexpr int MT = TW * MW * 16;
    __shared__ float biasS[CO];
    __shared__ float red[512];
    const int n  = blockIdx.y;
    const int t0 = blockIdx.x * MT;
    const int tid = threadIdx.x;
    for (int i = tid; i < CO; i += 256) biasS[i] = bias[i];
    __syncthreads();
    const int w = tid >> 6, lane = tid & 63;
    const int wt = w % TW, wco = w / TW;
    const int l16 = lane & 15, quad = lane >> 4;
    const bf16* gb = g + (size_t)n * T_g * 256;
    f4v acc[MW][NW];
    #pragma unroll
    for (int i = 0; i < MW; i++)
        #pragma unroll
        for (int j = 0; j < NW; j++) acc[i][j] = (f4v){0.f, 0.f, 0.f, 0.f};

    for (int kc = 0; kc < 8; kc++) {
        #pragma unroll
        for (int ks = 0; ks < 2; ks++) {
            s8v af[MW], bfr[NW];
            #pragma unroll
            for (int i = 0; i < MW; i++) {
                int t = t0 + wt * MW * 16 + i * 16 + l16;
                int tin = 2 * t - 1 + ks;
                bool valid = (unsigned)tin < (unsigned)T_g;
                int tc = valid ? tin : 0;
                af[i] = *(const s8v*)(gb + (size_t)tc * 256 + kc * 32 + quad * 8);
                if (!valid) af[i] = (s8v){0, 0, 0, 0, 0, 0, 0, 0};
            }
            #pragma unroll
            for (int j = 0; j < NW; j++) {
                int co = wco * NW * 16 + j * 16 + l16;
                bfr[j] = *(const s8v*)(Wp + (size_t)co * 512 + kc * 64 + ks * 32 + quad * 8);
            }
            #pragma unroll
            for (int i = 0; i < MW; i++)
                #pragma unroll
                for (int j = 0; j < NW; j++)
                    acc[i][j] = __builtin_amdgcn_mfma_f32_16x16x32_bf16(af[i], bfr[j], acc[i][j], 0, 0, 0);
        }
    }
    float lsum = 0.f, lsq = 0.f;
    #pragma unroll
    for (int i = 0; i < MW; i++) {
        #pragma unroll
        for (int r = 0; r < 4; r++) {
            int t = t0 + wt * MW * 16 + i * 16 + quad * 4 + r;
            if (t < T_out) {
                bf16* orow = hout + ((size_t)n * T_out + t) * CO;
                #pragma unroll
                for (int j = 0; j < NW; j++) {
                    int co = wco * NW * 16 + j * 16 + l16;
                    float v = acc[i][j][r] + biasS[co];
                    orow[co] = __float2bfloat16(v);
                    lsum += v; lsq += v * v;
                }
            }
        }
    }
    red[tid] = lsum; red[256 + tid] = lsq;
    __syncthreads();
    for (int st = 128; st > 0; st >>= 1) {
        if (tid < st) { red[tid] += red[tid + st]; red[256 + tid] += red[256 + tid + st]; }
        __syncthreads();
    }
    if (tid == 0) { atomicAdd(&ssum[n0 + n], red[0]); atomicAdd(&ssq[n0 + n], red[256]); }
}

// ---------------------------------------------------------------------------
// Tail kernel 1: GN5+GELU on h5T[n][t][c] + readout 1x1 + msg round-0 pre.
// Outputs lat0[n][t][d], A0, Bv0.
// ---------------------------------------------------------------------------
__global__ __launch_bounds__(256) void readout_pre_k(
    const bf16* __restrict__ h5T, const float* __restrict__ row,
    const float* __restrict__ rob, const float* __restrict__ g5,
    const float* __restrict__ be5, const float* __restrict__ ssum,
    const float* __restrict__ ssq, float invCT,
    const float* __restrict__ mw, const float* __restrict__ mb,
    float* __restrict__ lat0, float* __restrict__ A0, float* __restrict__ Bv0)
{
    __shared__ float lh[2112];   // [t][c] 33 x 64
    __shared__ float ll[2112];   // lat [t][d]
    __shared__ float lw[8192];
    __shared__ float lb[64];
    const int n = blockIdx.x, tid = threadIdx.x;
    const float mu = ssum[n] * invCT;
    const float rs = rsqrtf(ssq[n] * invCT - mu * mu + 1e-5f);
    for (int idx = tid; idx < 2112; idx += 256) {
        int c = idx & 63;
        float a = rs * g5[c];
        float v = __bfloat162float(h5T[(size_t)n * 2112 + idx]) * a + (be5[c] - mu * a);
        lh[idx] = gelu_f(v);
    }
    for (int idx = tid; idx < 4096; idx += 256) lw[idx] = row[idx];
    if (tid < 64) lb[tid] = rob[tid];
    __syncthreads();
    for (int idx = tid; idx < 2112; idx += 256) {
        int t = idx >> 6, d = idx & 63;
        float a = lb[d];
        #pragma unroll 8
        for (int c = 0; c < 64; c++) a += lh[t * 64 + c] * lw[c * 64 + d];
        ll[idx] = a;
        lat0[(size_t)n * 2112 + idx] = a;
    }
    __syncthreads();
    for (int idx = tid; idx < 8192; idx += 256) lw[idx] = mw[idx];
    if (tid < 64) lb[tid] = mb[tid];
    __syncthreads();
    for (int idx = tid; idx < 2112; idx += 256) {
        int t = idx >> 6, d = idx & 63;
        float a = 0.f, bb = lb[d];
        #pragma unroll 8
        for (int k = 0; k < 64; k++) {
            float xv = ll[t * 64 + k];
            a  += xv * lw[k * 64 + d];
            bb += xv * lw[(64 + k) * 64 + d];
        }
        A0[(size_t)n * 2112 + idx]  = a;
        Bv0[(size_t)n * 2112 + idx] = bb;
    }
}

// ---------------------------------------------------------------------------
// Tail kernel 2: msg round-0 combine + msg round-1 pre.
// ---------------------------------------------------------------------------
__global__ __launch_bounds__(256) void comb_pre_k(
    const float* __restrict__ lat0, const float* __restrict__ A0,
    const float* __restrict__ Bv0, const float* __restrict__ mw,
    const float* __restrict__ mb, float* __restrict__ lat1,
    float* __restrict__ A1, float* __restrict__ Bv1)
{
    __shared__ float ll[2112];
    __shared__ float lw[8192];
    __shared__ float lb[64];
    const int n = blockIdx.x, tid = threadIdx.x;
    const int b9 = (n / 9) * 9, j = n - b9;
    for (int idx = tid; idx < 2112; idx += 256) {
        float base = Bv0[(size_t)n * 2112 + idx];
        float s = 0.f;
        #pragma unroll
        for (int i = 0; i < 9; i++) {
            if (i == j) continue;
            s += fmaxf(A0[(size_t)(b9 + i) * 2112 + idx] + base, 0.f);
        }
        float v = lat0[(size_t)n * 2112 + idx] + s * 0.125f;
        ll[idx] = v;
        lat1[(size_t)n * 2112 + idx] = v;
    }
    for (int idx = tid; idx < 8192; idx += 256) lw[idx] = mw[idx];
    if (tid < 64) lb[tid] = mb[tid];
    __syncthreads();
    for (int idx = tid; idx < 2112; idx += 256) {
        int t = idx >> 6, d = idx & 63;
        float a = 0.f, bb = lb[d];
        #pragma unroll 8
        for (int k = 0; k < 64; k++) {
            float xv = ll[t * 64 + k];
            a  += xv * lw[k * 64 + d];
            bb += xv * lw[(64 + k) * 64 + d];
        }
        A1[(size_t)n * 2112 + idx]  = a;
        Bv1[(size_t)n * 2112 + idx] = bb;
    }
}

// ---------------------------------------------------------------------------
// Tail kernel 3: msg round-1 combine + view-sum + readout MLP + projection.
// ---------------------------------------------------------------------------
__global__ __launch_bounds__(256) void final2_k(
    const float* __restrict__ lat1, const float* __restrict__ A1,
    const float* __restrict__ Bv1,
    const float* __restrict__ w1, const float* __restrict__ b1,
    const float* __restrict__ w2, const float* __restrict__ b2,
    const float* __restrict__ pw, const float* __restrict__ pb,
    float* __restrict__ out)
{
    __shared__ float ly[2112], lz[2112];
    __shared__ float lw1[4096], lw2[4096], lpw[2048];
    __shared__ float lb1[64], lb2[64], lpb[32];
    const int b = blockIdx.x, tid = threadIdx.x;
    for (int idx = tid; idx < 4096; idx += 256) { lw1[idx] = w1[idx]; lw2[idx] = w2[idx]; }
    for (int idx = tid; idx < 2048; idx += 256) lpw[idx] = pw[idx];
    if (tid < 64) { lb1[tid] = b1[tid]; lb2[tid] = b2[tid]; }
    if (tid < 32) lpb[tid] = pb[tid];
    for (int idx = tid; idx < 2112; idx += 256) {
        float Av[9], Bb[9], s = 0.f;
        #pragma unroll
        for (int jj = 0; jj < 9; jj++) {
            size_t off = ((size_t)(b * 9 + jj)) * 2112 + idx;
            Av[jj] = A1[off];
            Bb[jj] = Bv1[off];
            s += lat1[off];
        }
        float m = 0.f;
        #pragma unroll
        for (int jj = 0; jj < 9; jj++) {
            float rowsum = 0.f;
            #pragma unroll
            for (int ii = 0; ii < 9; ii++) rowsum += fmaxf(Av[ii] + Bb[jj], 0.f);
            m += rowsum - fmaxf(Av[jj] + Bb[jj], 0.f);
        }
        ly[idx] = s + m * 0.125f;
    }
    __syncthreads();
    for (int idx = tid; idx < 2112; idx += 256) {
        int t = idx >> 6, d = idx & 63;
        float s = lb1[d];
        #pragma unroll 8
        for (int k = 0; k < 64; k++) s += ly[t * 64 + k] * lw1[k * 64 + d];
        lz[idx] = fmaxf(s, 0.f);
    }
    __syncthreads();
    for (int idx = tid; idx < 2112; idx += 256) {
        int t = idx >> 6, d = idx & 63;
        float s = lb2[d];
        #pragma unroll 8
        for (int k = 0; k < 64; k++) s += lz[t * 64 + k] * lw2[k * 64 + d];
        ly[idx] = s * (1.f / 9.f);
    }
    __syncthreads();
    for (int idx = tid; idx < 1056; idx += 256) {
        int e = idx / 33, t = idx - e * 33;
        float s = lpb[e];
        #pragma unroll 8
        for (int d = 0; d < 64; d++) s += ly[t * 64 + d] * lpw[d * 32 + e];
        out[(size_t)b * 1056 + idx] = s;
    }
}

// ---------------------------------------------------------------------------
extern "C" void kernel_launch(void* const* d_in, const int* in_sizes, int n_in,
                              void* d_out, int out_size, void* d_ws, size_t ws_size,
                              hipStream_t stream)
{
    const float* x = (const float*)d_in[0];
    const float* cw[6]; const float* cb[6]; const float* gg[6]; const float* gb[6];
    for (int l = 0; l < 6; l++) {
        cw[l] = (const float*)d_in[1 + 4 * l];
        cb[l] = (const float*)d_in[2 + 4 * l];
        gg[l] = (const float*)d_in[3 + 4 * l];
        gb[l] = (const float*)d_in[4 + 4 * l];
    }
    const float* ro_w = (const float*)d_in[25];
    const float* ro_b = (const float*)d_in[26];
    const float* mw0  = (const float*)d_in[27];
    const float* mb0  = (const float*)d_in[28];
    const float* mw1  = (const float*)d_in[29];
    const float* mb1  = (const float*)d_in[30];
    const float* rw1  = (const float*)d_in[31];
    const float* rb1  = (const float*)d_in[32];
    const float* rw2  = (const float*)d_in[33];
    const float* rb2  = (const float*)d_in[34];
    const float* pw   = (const float*)d_in[35];
    const float* pb   = (const float*)d_in[36];

    // ---- workspace (ws_size = 268,435,456 B measured; peak ~260.1 MB) ----
    // All activation buffers TRANSPOSED: [n][t][ci].
    char* ws = (char*)d_ws;
    bf16* h1T  = (bf16*)(ws);                 // [576][501][256] 147,750,912 B
    bf16* h0gT = (bf16*)(ws + 147750912);     // [192][1000][256] 98,304,000 B (chunk)
    bf16* h2T  = (bf16*)(ws + 147750912);     // [576][251][256] (h0gT dead)
    bf16* h3T  = (bf16*)(ws + 221773824);     // [576][126][256] -> 258,932,736
    bf16* h4T  = (bf16*)(ws);                 // [576][64][256]  (h1T dead)
    bf16* h5T  = (bf16*)(ws + 147750912);     // [576][33][64]   (h2T dead)
    float* lat0 = (float*)(ws);               // 6 x 4,866,048 B (h4T dead after L5)
    float* A0   = lat0 + 1216512;
    float* Bv0  = A0   + 1216512;
    float* lat1 = Bv0  + 1216512;
    float* A1   = lat1 + 1216512;
    float* Bv1  = A1   + 1216512;
    float* stat  = (float*)(ws + 258932736);
    float* mu0   = stat;
    float* rstd0 = stat + 576;
    float* coef  = stat + 1152;               // 16
    float* ssumA = stat + 1168;               // 5 x 576
    float* ssqA  = ssumA + 5 * 576;
    bf16*  Wp    = (bf16*)(ws + 258965504);   // 557,056 bf16 -> 260,079,616
    #define SSUM(l) (ssumA + ((l) - 1) * 576)
    #define SSQ(l)  (ssqA  + ((l) - 1) * 576)

    zero_k<<<(5760 + 255) / 256, 256, 0, stream>>>(ssumA, 2 * 5 * 576);
    wcvt_k<<<(557056 + 255) / 256, 256, 0, stream>>>(cw[1], cw[2], cw[3], cw[4], cw[5], Wp);
    m0red_k<<<1, 256, 0, stream>>>(cw[0], cb[0], coef);
    c0stats_k<<<576, 256, 0, stream>>>(x, coef, mu0, rstd0);

    // ---- layer 1: h0gT (chunked x3) + barrier-free GEMM ----
    for (int c = 0; c < 3; c++) {
        int n0 = c * 192;
        h0gT_k<<<dim3(32, 192), 256, 0, stream>>>(x, cw[0], cb[0], gg[0], gb[0], mu0, rstd0, h0gT, n0);
        convG_k<2, 2, 2, 8><<<dim3(8, 192), 256, 0, stream>>>(
            h0gT, Wp, cb[1], h1T + (size_t)n0 * 501 * 256, SSUM(1), SSQ(1), 1000, 501, n0);
    }
    gn_geluT_k<256, 501><<<(9234432 + 255) / 256, 256, 0, stream>>>(
        h1T, SSUM(1), SSQ(1), gg[1], gb[1], 1.f / (256.f * 501.f));

    // ---- layer 2 ----
    convG_k<2, 2, 2, 8><<<dim3(4, 576), 256, 0, stream>>>(
        h1T, Wp + 131072, cb[2], h2T, SSUM(2), SSQ(2), 501, 251, 0);
    gn_geluT_k<256, 251><<<(4626432 + 255) / 256, 256, 0, stream>>>(
        h2T, SSUM(2), SSQ(2), gg[2], gb[2], 1.f / (256.f * 251.f));

    // ---- layer 3 ----
    convG_k<2, 2, 2, 8><<<dim3(2, 576), 256, 0, stream>>>(
        h2T, Wp + 262144, cb[3], h3T, SSUM(3), SSQ(3), 251, 126, 0);
    gn_geluT_k<256, 126><<<(2322432 + 255) / 256, 256, 0, stream>>>(
        h3T, SSUM(3), SSQ(3), gg[3], gb[3], 1.f / (256.f * 126.f));

    // ---- layer 4 ----
    convG_k<2, 2, 2, 8><<<dim3(1, 576), 256, 0, stream>>>(
        h3T, Wp + 393216, cb[4], h4T, SSUM(4), SSQ(4), 126, 64, 0);
    gn_geluT_k<256, 64><<<(1179648 + 255) / 256, 256, 0, stream>>>(
        h4T, SSUM(4), SSQ(4), gg[4], gb[4], 1.f / (256.f * 64.f));

    // ---- layer 5 (CO=64) ----
    convG_k<4, 1, 1, 4><<<dim3(1, 576), 256, 0, stream>>>(
        h4T, Wp + 524288, cb[5], h5T, SSUM(5), SSQ(5), 64, 33, 0);

    // ---- fused tail: readout+pre0 -> comb0+pre1 -> comb1+sum+MLP+proj ----
    readout_pre_k<<<576, 256, 0, stream>>>(h5T, ro_w, ro_b, gg[5], gb[5],
                                           SSUM(5), SSQ(5), 1.f / (64.f * 33.f),
                                           mw0, mb0, lat0, A0, Bv0);
    comb_pre_k<<<576, 256, 0, stream>>>(lat0, A0, Bv0, mw1, mb1, lat1, A1, Bv1);
    final2_k<<<64, 256, 0, stream>>>(lat1, A1, Bv1, rw1, rb1, rw2, rb2, pw, pb, (float*)d_out);
}

// Round 7
// 894.995 us; speedup vs baseline: 1.3744x; 1.3744x over previous
//
#include <hip/hip_runtime.h>
#include <hip/hip_bf16.h>

typedef __hip_bfloat16 bf16;
typedef __attribute__((ext_vector_type(8))) short s8v;   // 8 bf16 (16B)
typedef __attribute__((ext_vector_type(4))) float f4v;   // 4 f32 (C/D frag)

// Branch-free erf (A&S 7.1.26), |err| < 1.5e-7 — exact at bf16 resolution.
__device__ __forceinline__ float erf_approx(float x) {
    float ax = fabsf(x);
    float t = 1.0f / (1.0f + 0.3275911f * ax);
    float p = t * (0.254829592f + t * (-0.284496736f + t * (1.421413741f
              + t * (-1.453152027f + t * 1.061405429f))));
    float r = 1.0f - p * __expf(-ax * ax);
    return copysignf(r, x);
}
__device__ __forceinline__ float gelu_f(float v) {
    return 0.5f * v * (1.f + erf_approx(v * 0.70710678118654752440f));
}
__device__ __forceinline__ unsigned short f2bf_u(float f) {
    bf16 b = __float2bfloat16(f);
    return *(unsigned short*)&b;
}
__device__ __forceinline__ float bfu2f(unsigned short u) {
    bf16 b = *(bf16*)&u;
    return __bfloat162float(b);
}

// ---------------------------------------------------------------------------
__global__ __launch_bounds__(256) void zero_k(float* __restrict__ p, int n) {
    int i = blockIdx.x * 256 + threadIdx.x;
    if (i < n) p[i] = 0.f;
}

// ---------------------------------------------------------------------------
// Convert + K-PERMUTE conv weights W1..W5 fp32 -> bf16.
// Wp[co][kc*64 + s*32 + ci_l] = W[co][kc*32+ci_l][s]  (kc<8, s<2, ci_l<32)
// ---------------------------------------------------------------------------
__global__ __launch_bounds__(256) void wcvt_k(
    const float* __restrict__ w1, const float* __restrict__ w2,
    const float* __restrict__ w3, const float* __restrict__ w4,
    const float* __restrict__ w5, bf16* __restrict__ dst)
{
    int i = blockIdx.x * 256 + threadIdx.x;
    if (i >= 557056) return;
    const float* src; int li;
    if      (i < 131072) { src = w1; li = i; }
    else if (i < 262144) { src = w2; li = i - 131072; }
    else if (i < 393216) { src = w3; li = i - 262144; }
    else if (i < 524288) { src = w4; li = i - 393216; }
    else                 { src = w5; li = i - 524288; }
    int co = li >> 9, rem = li & 511;
    int kc = rem >> 6, rr = rem & 63;
    int s = rr >> 5, cil = rr & 31;
    dst[i] = __float2bfloat16(src[co * 512 + (kc * 32 + cil) * 2 + s]);
}

// ---------------------------------------------------------------------------
// conv0 channel-collapse coefficients (sum over co of v and v^2 as a
// quadratic form in (x0,x1,x2,1)).
// ---------------------------------------------------------------------------
__global__ __launch_bounds__(256) void m0red_k(
    const float* __restrict__ W0, const float* __restrict__ b0, float* __restrict__ coef)
{
    __shared__ float red[256];
    const int co = threadIdx.x;
    float w0 = W0[3 * co], w1 = W0[3 * co + 1], w2 = W0[3 * co + 2], b = b0[co];
    float vals[14] = {w0, w1, w2, b,
                      w0 * w0, w1 * w1, w2 * w2, b * b,
                      2.f * w0 * w1, 2.f * w0 * w2, 2.f * w1 * w2,
                      2.f * w0 * b, 2.f * w1 * b, 2.f * w2 * b};
    for (int k = 0; k < 14; k++) {
        red[co] = vals[k];
        __syncthreads();
        for (int st = 128; st > 0; st >>= 1) {
            if (co < st) red[co] += red[co + st];
            __syncthreads();
        }
        if (co == 0) coef[k] = red[0];
        __syncthreads();
    }
}

// ---------------------------------------------------------------------------
// GN0 stats per node via the collapsed quadratic form. One block per node.
// ---------------------------------------------------------------------------
__global__ __launch_bounds__(256) void c0stats_k(
    const float* __restrict__ x, const float* __restrict__ coef,
    float* __restrict__ mu0, float* __restrict__ rstd0)
{
    __shared__ float xsl[3008];
    __shared__ float red[512];
    const int n = blockIdx.x, tid = threadIdx.x;
    const float* xr = x + (size_t)n * 3000;
    for (int i = tid; i < 750; i += 256) *(float4*)&xsl[4 + 4 * i] = *(const float4*)(xr + 4 * i);
    if (tid < 4) xsl[tid] = 0.f;
    float c[14];
    #pragma unroll
    for (int k = 0; k < 14; k++) c[k] = coef[k];
    __syncthreads();
    float S = 0.f, Q = 0.f;
    if (tid < 250) {
        float f[16];
        #pragma unroll
        for (int k = 0; k < 4; k++) *(float4*)&f[4 * k] = *(const float4*)&xsl[12 * tid + 4 * k];
        #pragma unroll
        for (int j = 0; j < 4; j++) {
            float x0 = f[3 * j + 3], x1 = f[3 * j + 4], x2 = f[3 * j + 5];
            S += c[0] * x0 + c[1] * x1 + c[2] * x2 + c[3];
            Q += c[4] * x0 * x0 + c[5] * x1 * x1 + c[6] * x2 * x2 + c[7]
               + c[8] * x0 * x1 + c[9] * x0 * x2 + c[10] * x1 * x2
               + c[11] * x0 + c[12] * x1 + c[13] * x2;
        }
    }
    red[tid] = S; red[256 + tid] = Q;
    __syncthreads();
    for (int st = 128; st > 0; st >>= 1) {
        if (tid < st) { red[tid] += red[tid + st]; red[256 + tid] += red[256 + tid + st]; }
        __syncthreads();
    }
    if (tid == 0) {
        float m = red[0] * (1.f / 256000.f);
        float var = red[256] * (1.f / 256000.f) - m * m;
        mu0[n] = m;
        rstd0[n] = rsqrtf(var + 1e-5f);
    }
}

// ---------------------------------------------------------------------------
// h0gT[z][t][ci] = gelu(gn0(conv0(x))) bf16, TRANSPOSED layout, node-chunked.
// ---------------------------------------------------------------------------
__global__ __launch_bounds__(256) void h0gT_k(
    const float* __restrict__ x, const float* __restrict__ W0,
    const float* __restrict__ b0, const float* __restrict__ g0,
    const float* __restrict__ be0, const float* __restrict__ mu0,
    const float* __restrict__ rstd0, bf16* __restrict__ h0gT, int n0)
{
    __shared__ float xs[96];
    __shared__ float w0s[768];
    __shared__ float aco[256], cco[256];
    const int z = blockIdx.y;
    const int n = n0 + z;
    const int t0 = blockIdx.x * 32;
    const int tid = threadIdx.x;
    for (int i = tid; i < 768; i += 256) w0s[i] = W0[i];
    {
        float mu = mu0[n], rs = rstd0[n];
        float a = rs * g0[tid];
        aco[tid] = a;
        cco[tid] = (b0[tid] - mu) * a + be0[tid];
    }
    if (tid < 96) {
        int xg = 3 * t0 - 1 + tid;
        xs[tid] = (xg >= 0 && xg < 3000) ? x[(size_t)n * 3000 + xg] : 0.f;
    }
    __syncthreads();
    const int oct = tid & 31, ci0 = oct * 8;
    const int tq = tid >> 5;
    #pragma unroll
    for (int u = 0; u < 4; u++) {
        int tl = tq + 8 * u;
        int t = t0 + tl;
        if (t >= 1000) continue;
        float x0 = xs[3 * tl], x1 = xs[3 * tl + 1], x2 = xs[3 * tl + 2];
        ushort4 lo, hi;
        unsigned short* pu = (unsigned short*)&lo;
        #pragma unroll
        for (int jj = 0; jj < 8; jj++) {
            int ci = ci0 + jj;
            float conv = w0s[3 * ci] * x0 + w0s[3 * ci + 1] * x1 + w0s[3 * ci + 2] * x2;
            float v = gelu_f(conv * aco[ci] + cco[ci]);
            if (jj < 4) pu[jj] = f2bf_u(v);
            else ((unsigned short*)&hi)[jj - 4] = f2bf_u(v);
        }
        bf16* orow = h0gT + ((size_t)z * 1000 + t) * 256 + ci0;
        *(ushort4*)orow = lo;
        *(ushort4*)(orow + 4) = hi;
    }
}

// ---------------------------------------------------------------------------
// In-place GN + GELU on transposed conv output [n][T][C] (c = idx & (C-1)).
// ---------------------------------------------------------------------------
template<int C, int T>
__global__ __launch_bounds__(256) void gn_geluT_k(
    bf16* __restrict__ h, const float* __restrict__ ssum, const float* __restrict__ ssq,
    const float* __restrict__ gam, const float* __restrict__ bet, float invCT)
{
    constexpr unsigned CT = (unsigned)C * (unsigned)T;
    constexpr unsigned total = 576u * CT;
    unsigned I = (blockIdx.x * 256u + threadIdx.x) * 8u;
    if (I >= total) return;
    unsigned n = I / CT;
    unsigned c = I & (unsigned)(C - 1);
    float m = ssum[n] * invCT;
    float rs = rsqrtf(ssq[n] * invCT - m * m + 1e-5f);
    float4 g0 = *(const float4*)&gam[c], g1 = *(const float4*)&gam[c + 4];
    float4 b0 = *(const float4*)&bet[c], b1 = *(const float4*)&bet[c + 4];
    float ga[8] = {g0.x, g0.y, g0.z, g0.w, g1.x, g1.y, g1.z, g1.w};
    float be[8] = {b0.x, b0.y, b0.z, b0.w, b1.x, b1.y, b1.z, b1.w};
    s8v v8 = *(s8v*)&h[I];
    unsigned short* uu = (unsigned short*)&v8;
    #pragma unroll
    for (int j = 0; j < 8; j++) {
        float a = rs * ga[j];
        float v = bfu2f(uu[j]) * a + (be[j] - m * a);
        uu[j] = f2bf_u(gelu_f(v));
    }
    *(s8v*)&h[I] = v8;
}

// ===========================================================================
// Hybrid MFMA conv GEMM. A = activations gT[n][t][ci] staged in LDS
// (b128 global -> b128 ds_write, 2 slots/thread/chunk); B = permuted weights
// direct from global (L2-resident 256KB), loads issued before the barrier.
// Tile: MT = MW*16 t-rows x CO = 4*NW*16 co (4 waves along co).
// Output hout[n][t][co] (transposed) + GN stat atomics.
// ===========================================================================
template<int MW, int NW>
__global__ __launch_bounds__(256) void convT_k(
    const bf16* __restrict__ g, const bf16* __restrict__ Wp,
    const float* __restrict__ bias, bf16* __restrict__ hout,
    float* __restrict__ ssum, float* __restrict__ ssq,
    int T_g, int T_out, int n0)
{
    constexpr int CO = 4 * NW * 16;
    constexpr int MT = MW * 16;
    constexpr int NSLOT = MT * 8;          // 16B slots in the A tile per chunk
    __shared__ bf16 aT[MT * 64];           // [t][64 k-elems] rows of 128B
    __shared__ float biasS[CO];
    __shared__ float red[512];
    const int n  = blockIdx.y;
    const int t0 = blockIdx.x * MT;
    const int tid = threadIdx.x;
    for (int i = tid; i < CO; i += 256) biasS[i] = bias[i];
    const int w = tid >> 6, lane = tid & 63;
    const int l16 = lane & 15, quad = lane >> 4;
    const bf16* gb = g + (size_t)n * T_g * 256;
    f4v acc[MW][NW];
    #pragma unroll
    for (int i = 0; i < MW; i++)
        #pragma unroll
        for (int j = 0; j < NW; j++) acc[i][j] = (f4v){0.f, 0.f, 0.f, 0.f};

    for (int kc = 0; kc < 8; kc++) {
        // ---- stage A tile: slot (t, j): j = ks*4+q; data = gT[2(t0+t)-1+ks][kc*32+q*8 ..+8]
        #pragma unroll
        for (int u = 0; u < (NSLOT + 255) / 256; u++) {
            int slot = tid + 256 * u;
            if (NSLOT % 256 != 0 && slot >= NSLOT) break;
            int t = slot >> 3, j = slot & 7;
            int ks = j >> 2, q = j & 3;
            int tin = 2 * (t0 + t) - 1 + ks;
            s8v v = (s8v){0, 0, 0, 0, 0, 0, 0, 0};
            if ((unsigned)tin < (unsigned)T_g)
                v = *(const s8v*)(gb + (size_t)tin * 256 + kc * 32 + q * 8);
            *(s8v*)&aT[slot * 8] = v;
        }
        // ---- B fragments direct from global (independent of LDS -> overlaps barrier)
        s8v bfr[2][NW];
        #pragma unroll
        for (int ks = 0; ks < 2; ks++)
            #pragma unroll
            for (int j = 0; j < NW; j++) {
                int co = w * NW * 16 + j * 16 + l16;
                bfr[ks][j] = *(const s8v*)(Wp + (size_t)co * 512 + kc * 64 + ks * 32 + quad * 8);
            }
        __syncthreads();
        #pragma unroll
        for (int ks = 0; ks < 2; ks++) {
            s8v af[MW];
            #pragma unroll
            for (int i = 0; i < MW; i++)
                af[i] = *(const s8v*)&aT[(i * 16 + l16) * 64 + ks * 32 + quad * 8];
            #pragma unroll
            for (int i = 0; i < MW; i++)
                #pragma unroll
                for (int j = 0; j < NW; j++)
                    acc[i][j] = __builtin_amdgcn_mfma_f32_16x16x32_bf16(af[i], bfr[ks][j], acc[i][j], 0, 0, 0);
        }
        __syncthreads();
    }
    float lsum = 0.f, lsq = 0.f;
    #pragma unroll
    for (int i = 0; i < MW; i++) {
        #pragma unroll
        for (int r = 0; r < 4; r++) {
            int t = t0 + i * 16 + quad * 4 + r;
            if (t < T_out) {
                bf16* orow = hout + ((size_t)n * T_out + t) * CO;
                #pragma unroll
                for (int j = 0; j < NW; j++) {
                    int co = w * NW * 16 + j * 16 + l16;
                    float v = acc[i][j][r] + biasS[co];
                    orow[co] = __float2bfloat16(v);
                    lsum += v; lsq += v * v;
                }
            }
        }
    }
    red[tid] = lsum; red[256 + tid] = lsq;
    __syncthreads();
    for (int st = 128; st > 0; st >>= 1) {
        if (tid < st) { red[tid] += red[tid + st]; red[256 + tid] += red[256 + tid + st]; }
        __syncthreads();
    }
    if (tid == 0) { atomicAdd(&ssum[n0 + n], red[0]); atomicAdd(&ssq[n0 + n], red[256]); }
}

// ---------------------------------------------------------------------------
// Tail kernel 1: GN5+GELU on h5T[n][t][c] + readout 1x1 + msg round-0 pre.
// ---------------------------------------------------------------------------
__global__ __launch_bounds__(256) void readout_pre_k(
    const bf16* __restrict__ h5T, const float* __restrict__ row,
    const float* __restrict__ rob, const float* __restrict__ g5,
    const float* __restrict__ be5, const float* __restrict__ ssum,
    const float* __restrict__ ssq, float invCT,
    const float* __restrict__ mw, const float* __restrict__ mb,
    float* __restrict__ lat0, float* __restrict__ A0, float* __restrict__ Bv0)
{
    __shared__ float lh[2112];   // [t][c] 33 x 64
    __shared__ float ll[2112];   // lat [t][d]
    __shared__ float lw[8192];
    __shared__ float lb[64];
    const int n = blockIdx.x, tid = threadIdx.x;
    const float mu = ssum[n] * invCT;
    const float rs = rsqrtf(ssq[n] * invCT - mu * mu + 1e-5f);
    for (int idx = tid; idx < 2112; idx += 256) {
        int c = idx & 63;
        float a = rs * g5[c];
        float v = __bfloat162float(h5T[(size_t)n * 2112 + idx]) * a + (be5[c] - mu * a);
        lh[idx] = gelu_f(v);
    }
    for (int idx = tid; idx < 4096; idx += 256) lw[idx] = row[idx];
    if (tid < 64) lb[tid] = rob[tid];
    __syncthreads();
    for (int idx = tid; idx < 2112; idx += 256) {
        int t = idx >> 6, d = idx & 63;
        float a = lb[d];
        #pragma unroll 8
        for (int c = 0; c < 64; c++) a += lh[t * 64 + c] * lw[c * 64 + d];
        ll[idx] = a;
        lat0[(size_t)n * 2112 + idx] = a;
    }
    __syncthreads();
    for (int idx = tid; idx < 8192; idx += 256) lw[idx] = mw[idx];
    if (tid < 64) lb[tid] = mb[tid];
    __syncthreads();
    for (int idx = tid; idx < 2112; idx += 256) {
        int t = idx >> 6, d = idx & 63;
        float a = 0.f, bb = lb[d];
        #pragma unroll 8
        for (int k = 0; k < 64; k++) {
            float xv = ll[t * 64 + k];
            a  += xv * lw[k * 64 + d];
            bb += xv * lw[(64 + k) * 64 + d];
        }
        A0[(size_t)n * 2112 + idx]  = a;
        Bv0[(size_t)n * 2112 + idx] = bb;
    }
}

// ---------------------------------------------------------------------------
// Tail kernel 2: msg round-0 combine + msg round-1 pre.
// ---------------------------------------------------------------------------
__global__ __launch_bounds__(256) void comb_pre_k(
    const float* __restrict__ lat0, const float* __restrict__ A0,
    const float* __restrict__ Bv0, const float* __restrict__ mw,
    const float* __restrict__ mb, float* __restrict__ lat1,
    float* __restrict__ A1, float* __restrict__ Bv1)
{
    __shared__ float ll[2112];
    __shared__ float lw[8192];
    __shared__ float lb[64];
    const int n = blockIdx.x, tid = threadIdx.x;
    const int b9 = (n / 9) * 9, j = n - b9;
    for (int idx = tid; idx < 2112; idx += 256) {
        float base = Bv0[(size_t)n * 2112 + idx];
        float s = 0.f;
        #pragma unroll
        for (int i = 0; i < 9; i++) {
            if (i == j) continue;
            s += fmaxf(A0[(size_t)(b9 + i) * 2112 + idx] + base, 0.f);
        }
        float v = lat0[(size_t)n * 2112 + idx] + s * 0.125f;
        ll[idx] = v;
        lat1[(size_t)n * 2112 + idx] = v;
    }
    for (int idx = tid; idx < 8192; idx += 256) lw[idx] = mw[idx];
    if (tid < 64) lb[tid] = mb[tid];
    __syncthreads();
    for (int idx = tid; idx < 2112; idx += 256) {
        int t = idx >> 6, d = idx & 63;
        float a = 0.f, bb = lb[d];
        #pragma unroll 8
        for (int k = 0; k < 64; k++) {
            float xv = ll[t * 64 + k];
            a  += xv * lw[k * 64 + d];
            bb += xv * lw[(64 + k) * 64 + d];
        }
        A1[(size_t)n * 2112 + idx]  = a;
        Bv1[(size_t)n * 2112 + idx] = bb;
    }
}

// ---------------------------------------------------------------------------
// Tail kernel 3: msg round-1 combine + view-sum + readout MLP + projection.
// ---------------------------------------------------------------------------
__global__ __launch_bounds__(256) void final2_k(
    const float* __restrict__ lat1, const float* __restrict__ A1,
    const float* __restrict__ Bv1,
    const float* __restrict__ w1, const float* __restrict__ b1,
    const float* __restrict__ w2, const float* __restrict__ b2,
    const float* __restrict__ pw, const float* __restrict__ pb,
    float* __restrict__ out)
{
    __shared__ float ly[2112], lz[2112];
    __shared__ float lw1[4096], lw2[4096], lpw[2048];
    __shared__ float lb1[64], lb2[64], lpb[32];
    const int b = blockIdx.x, tid = threadIdx.x;
    for (int idx = tid; idx < 4096; idx += 256) { lw1[idx] = w1[idx]; lw2[idx] = w2[idx]; }
    for (int idx = tid; idx < 2048; idx += 256) lpw[idx] = pw[idx];
    if (tid < 64) { lb1[tid] = b1[tid]; lb2[tid] = b2[tid]; }
    if (tid < 32) lpb[tid] = pb[tid];
    for (int idx = tid; idx < 2112; idx += 256) {
        float Av[9], Bb[9], s = 0.f;
        #pragma unroll
        for (int jj = 0; jj < 9; jj++) {
            size_t off = ((size_t)(b * 9 + jj)) * 2112 + idx;
            Av[jj] = A1[off];
            Bb[jj] = Bv1[off];
            s += lat1[off];
        }
        float m = 0.f;
        #pragma unroll
        for (int jj = 0; jj < 9; jj++) {
            float rowsum = 0.f;
            #pragma unroll
            for (int ii = 0; ii < 9; ii++) rowsum += fmaxf(Av[ii] + Bb[jj], 0.f);
            m += rowsum - fmaxf(Av[jj] + Bb[jj], 0.f);
        }
        ly[idx] = s + m * 0.125f;
    }
    __syncthreads();
    for (int idx = tid; idx < 2112; idx += 256) {
        int t = idx >> 6, d = idx & 63;
        float s = lb1[d];
        #pragma unroll 8
        for (int k = 0; k < 64; k++) s += ly[t * 64 + k] * lw1[k * 64 + d];
        lz[idx] = fmaxf(s, 0.f);
    }
    __syncthreads();
    for (int idx = tid; idx < 2112; idx += 256) {
        int t = idx >> 6, d = idx & 63;
        float s = lb2[d];
        #pragma unroll 8
        for (int k = 0; k < 64; k++) s += lz[t * 64 + k] * lw2[k * 64 + d];
        ly[idx] = s * (1.f / 9.f);
    }
    __syncthreads();
    for (int idx = tid; idx < 1056; idx += 256) {
        int e = idx / 33, t = idx - e * 33;
        float s = lpb[e];
        #pragma unroll 8
        for (int d = 0; d < 64; d++) s += ly[t * 64 + d] * lpw[d * 32 + e];
        out[(size_t)b * 1056 + idx] = s;
    }
}

// ---------------------------------------------------------------------------
extern "C" void kernel_launch(void* const* d_in, const int* in_sizes, int n_in,
                              void* d_out, int out_size, void* d_ws, size_t ws_size,
                              hipStream_t stream)
{
    const float* x = (const float*)d_in[0];
    const float* cw[6]; const float* cb[6]; const float* gg[6]; const float* gb[6];
    for (int l = 0; l < 6; l++) {
        cw[l] = (const float*)d_in[1 + 4 * l];
        cb[l] = (const float*)d_in[2 + 4 * l];
        gg[l] = (const float*)d_in[3 + 4 * l];
        gb[l] = (const float*)d_in[4 + 4 * l];
    }
    const float* ro_w = (const float*)d_in[25];
    const float* ro_b = (const float*)d_in[26];
    const float* mw0  = (const float*)d_in[27];
    const float* mb0  = (const float*)d_in[28];
    const float* mw1  = (const float*)d_in[29];
    const float* mb1  = (const float*)d_in[30];
    const float* rw1  = (const float*)d_in[31];
    const float* rb1  = (const float*)d_in[32];
    const float* rw2  = (const float*)d_in[33];
    const float* rb2  = (const float*)d_in[34];
    const float* pw   = (const float*)d_in[35];
    const float* pb   = (const float*)d_in[36];

    // ---- workspace (ws_size = 268,435,456 B measured; peak ~260.1 MB) ----
    // All activation buffers TRANSPOSED: [n][t][ci].
    char* ws = (char*)d_ws;
    bf16* h1T  = (bf16*)(ws);                 // [576][501][256] 147,750,912 B
    bf16* h0gT = (bf16*)(ws + 147750912);     // [192][1000][256] 98,304,000 B (chunk)
    bf16* h2T  = (bf16*)(ws + 147750912);     // [576][251][256] (h0gT dead)
    bf16* h3T  = (bf16*)(ws + 221773824);     // [576][126][256] -> 258,932,736
    bf16* h4T  = (bf16*)(ws);                 // [576][64][256]  (h1T dead)
    bf16* h5T  = (bf16*)(ws + 147750912);     // [576][33][64]   (h2T dead)
    float* lat0 = (float*)(ws);               // 6 x 4,866,048 B (h4T dead after L5)
    float* A0   = lat0 + 1216512;
    float* Bv0  = A0   + 1216512;
    float* lat1 = Bv0  + 1216512;
    float* A1   = lat1 + 1216512;
    float* Bv1  = A1   + 1216512;
    float* stat  = (float*)(ws + 258932736);
    float* mu0   = stat;
    float* rstd0 = stat + 576;
    float* coef  = stat + 1152;               // 16
    float* ssumA = stat + 1168;               // 5 x 576
    float* ssqA  = ssumA + 5 * 576;
    bf16*  Wp    = (bf16*)(ws + 258965504);   // 557,056 bf16 -> 260,079,616
    #define SSUM(l) (ssumA + ((l) - 1) * 576)
    #define SSQ(l)  (ssqA  + ((l) - 1) * 576)

    zero_k<<<(5760 + 255) / 256, 256, 0, stream>>>(ssumA, 2 * 5 * 576);
    wcvt_k<<<(557056 + 255) / 256, 256, 0, stream>>>(cw[1], cw[2], cw[3], cw[4], cw[5], Wp);
    m0red_k<<<1, 256, 0, stream>>>(cw[0], cb[0], coef);
    c0stats_k<<<576, 256, 0, stream>>>(x, coef, mu0, rstd0);

    // ---- layer 1: h0gT (chunked x3) + LDS-A / direct-B GEMM ----
    for (int c = 0; c < 3; c++) {
        int n0 = c * 192;
        h0gT_k<<<dim3(32, 192), 256, 0, stream>>>(x, cw[0], cb[0], gg[0], gb[0], mu0, rstd0, h0gT, n0);
        convT_k<4, 4><<<dim3(8, 192), 256, 0, stream>>>(
            h0gT, Wp, cb[1], h1T + (size_t)n0 * 501 * 256, SSUM(1), SSQ(1), 1000, 501, n0);
    }
    gn_geluT_k<256, 501><<<(9234432 + 255) / 256, 256, 0, stream>>>(
        h1T, SSUM(1), SSQ(1), gg[1], gb[1], 1.f / (256.f * 501.f));

    // ---- layer 2 ----
    convT_k<4, 4><<<dim3(4, 576), 256, 0, stream>>>(
        h1T, Wp + 131072, cb[2], h2T, SSUM(2), SSQ(2), 501, 251, 0);
    gn_geluT_k<256, 251><<<(4626432 + 255) / 256, 256, 0, stream>>>(
        h2T, SSUM(2), SSQ(2), gg[2], gb[2], 1.f / (256.f * 251.f));

    // ---- layer 3 ----
    convT_k<4, 4><<<dim3(2, 576), 256, 0, stream>>>(
        h2T, Wp + 262144, cb[3], h3T, SSUM(3), SSQ(3), 251, 126, 0);
    gn_geluT_k<256, 126><<<(2322432 + 255) / 256, 256, 0, stream>>>(
        h3T, SSUM(3), SSQ(3), gg[3], gb[3], 1.f / (256.f * 126.f));

    // ---- layer 4 ----
    convT_k<4, 4><<<dim3(1, 576), 256, 0, stream>>>(
        h3T, Wp + 393216, cb[4], h4T, SSUM(4), SSQ(4), 126, 64, 0);
    gn_geluT_k<256, 64><<<(1179648 + 255) / 256, 256, 0, stream>>>(
        h4T, SSUM(4), SSQ(4), gg[4], gb[4], 1.f / (256.f * 64.f));

    // ---- layer 5 (CO=64) ----
    convT_k<3, 1><<<dim3(1, 576), 256, 0, stream>>>(
        h4T, Wp + 524288, cb[5], h5T, SSUM(5), SSQ(5), 64, 33, 0);

    // ---- fused tail: readout+pre0 -> comb0+pre1 -> comb1+sum+MLP+proj ----
    readout_pre_k<<<576, 256, 0, stream>>>(h5T, ro_w, ro_b, gg[5], gb[5],
                                           SSUM(5), SSQ(5), 1.f / (64.f * 33.f),
                                           mw0, mb0, lat0, A0, Bv0);
    comb_pre_k<<<576, 256, 0, stream>>>(lat0, A0, Bv0, mw1, mb1, lat1, A1, Bv1);
    final2_k<<<64, 256, 0, stream>>>(lat1, A1, Bv1, rw1, rb1, rw2, rb2, pw, pb, (float*)d_out);
}